// Round 23
// baseline (212.174 us; speedup 1.0000x reference)
//
#include <hip/hip_runtime.h>

typedef short short8 __attribute__((ext_vector_type(8)));
typedef short short4v __attribute__((ext_vector_type(4)));
typedef float f32x4 __attribute__((ext_vector_type(4)));

#define NT 550
#define NS 2209
#define NP 12
#define NBK 69
#define SC_NGRP 18
#define SC_GBK 4
#define SC_TW 32
#define NSG 139
#define GNRM 3.9894228040143f

typedef unsigned short bfu;

__device__ __forceinline__ bfu f2bf(float f) {
    unsigned int u = __float_as_uint(f);
    unsigned int r = (u + 0x7fffu + ((u >> 16) & 1u)) >> 16;
    return (bfu)r;
}

__device__ __forceinline__ float sigm(float x) {
    return __builtin_amdgcn_rcpf(1.0f + __expf(-x));
}

// ---------- weight conversion: fp32 -> transposed bf16 ----------
__global__ void k_prep(const float* __restrict__ W2, const float* __restrict__ W3,
                       const float* __restrict__ W4,
                       bfu* __restrict__ w2h, bfu* __restrict__ w3h, bfu* __restrict__ w4h) {
    int id = blockIdx.x * 256 + threadIdx.x;
    if (id < 8192) {
        int c = id >> 6, k = id & 63;
        w2h[id] = f2bf(W2[k * 128 + c]);
    } else if (id < 8192 + 32768) {
        int j = id - 8192;
        int c = j >> 7, k = j & 127;
        w3h[j] = f2bf(W3[k * 256 + c]);
    } else {
        int j = id - 40960;
        int s = j >> 8, k = j & 255;
        w4h[j] = f2bf(s < NS ? W4[k * NS + s] : 0.0f);
    }
}

// ---------- bucketing ----------
__global__ void k_count(const float* __restrict__ el, int* __restrict__ counts) {
    int id = blockIdx.x * 256 + threadIdx.x;
    float z = el[id * 3 + 2];
    int bk = (int)(z * 0.125f);
    bk = bk < 0 ? 0 : (bk > NBK - 1 ? NBK - 1 : bk);
    atomicAdd(&counts[(id >> 13) * NBK + bk], 1);
}

__global__ void k_scan(const int* __restrict__ counts, int* __restrict__ offs) {
    __shared__ int a[512];
    int tid = threadIdx.x;
    int v = (tid < 4 * NBK) ? counts[tid] : 0;
    a[tid] = v;
    __syncthreads();
    for (int s = 1; s < 512; s <<= 1) {
        int t = (tid >= s) ? a[tid - s] : 0;
        __syncthreads();
        a[tid] += t;
        __syncthreads();
    }
    if (tid < 4 * NBK) offs[tid] = a[tid] - v;
}

__global__ void k_scatter(const float* __restrict__ el, const float* __restrict__ wt,
                          const int* __restrict__ offs, int* __restrict__ cur,
                          int* __restrict__ inv, float4* __restrict__ elp) {
    int id = blockIdx.x * 256 + threadIdx.x;
    float x = el[id * 3], y = el[id * 3 + 1], z = el[id * 3 + 2];
    int bk = (int)(z * 0.125f);
    bk = bk < 0 ? 0 : (bk > NBK - 1 ? NBK - 1 : bk);
    int key = (id >> 13) * NBK + bk;
    int pos = offs[key] + atomicAdd(&cur[key], 1);
    inv[id] = pos;
    elp[pos] = make_float4(x, y, z, wt[id]);
}

// ---------- phase A: sipm MLP layers 1-3 -> s3p (BUCKET-SORTED, bf16) ----------
__global__ __launch_bounds__(256, 1) void k_mlp(
    const float* __restrict__ el,
    const float* __restrict__ Ws1, const float* __restrict__ bs1,
    const float* __restrict__ bs2, const float* __restrict__ bs3,
    const bfu* __restrict__ w2h, const bfu* __restrict__ w3h,
    const int* __restrict__ inv, bfu* __restrict__ s3p) {

    __shared__ __align__(16) bfu bufA[32768];
    __shared__ __align__(16) bfu w3t[32768];
    __shared__ float xyb[256];
    __shared__ float s1w[128];
    __shared__ float b1s[64], b2s[128], b3s[256];

    bfu* h1t = bufA;
    bfu* w2t = bufA + 8192;
    bfu* h2t = bufA + 16384;

    const int tid = threadIdx.x;
    const int wv = tid >> 6, ln = tid & 63;
    const int e0 = blockIdx.x * 128;

    if (tid < 128) s1w[tid] = Ws1[tid];
    if (tid < 64) b1s[tid] = bs1[tid];
    if (tid < 128) b2s[tid] = bs2[tid];
    b3s[tid] = bs3[tid];

    if (tid < 128) {
        int e = e0 + tid;
        xyb[tid * 2] = el[e * 3]; xyb[tid * 2 + 1] = el[e * 3 + 1];
    }
    for (int i = 0; i < 4; ++i) {
        int cid = i * 256 + tid;
        int row = cid >> 3, c5 = cid & 7;
        short8 v = *(const short8*)(const void*)&w2h[row * 64 + c5 * 8];
        *(short8*)(void*)&w2t[row * 64 + ((c5 ^ (row & 7)) * 8)] = v;
    }
    for (int i = 0; i < 16; ++i) {
        int cid = i * 256 + tid;
        int row = cid >> 4, c5 = cid & 15;
        short8 v = *(const short8*)(const void*)&w3h[row * 128 + c5 * 8];
        *(short8*)(void*)&w3t[row * 128 + ((c5 ^ (row & 7)) * 8)] = v;
    }
    __syncthreads();

    {
        int n = tid & 127;
        int j0 = (tid >> 7) * 32;
        float xx = xyb[n * 2], yy = xyb[n * 2 + 1];
        for (int jj = 0; jj < 32; ++jj) {
            int j = j0 + jj;
            float h = sigm(xx * s1w[j] + yy * s1w[64 + j] + b1s[j]);
            h1t[n * 64 + (((j >> 3) ^ (n & 7)) * 8) + (j & 7)] = f2bf(h);
        }
    }
    __syncthreads();

    {
        const int mr = (wv >> 1) * 64;
        const int nc = (wv & 1) * 64;
        f32x4 acc[4][4];
        for (int m = 0; m < 4; ++m) for (int nf = 0; nf < 4; ++nf) acc[m][nf] = (f32x4){0.f, 0.f, 0.f, 0.f};
        for (int kk = 0; kk < 2; ++kk) {
            int kc = kk * 4 + (ln >> 4);
            short8 af[4], bf[4];
            for (int m = 0; m < 4; ++m) {
                int row = mr + 16 * m + (ln & 15);
                af[m] = *(const short8*)(const void*)&h1t[row * 64 + ((kc ^ (row & 7)) * 8)];
            }
            for (int nf = 0; nf < 4; ++nf) {
                int c = nc + 16 * nf + (ln & 15);
                bf[nf] = *(const short8*)(const void*)&w2t[c * 64 + ((kc ^ (c & 7)) * 8)];
            }
            for (int m = 0; m < 4; ++m)
                for (int nf = 0; nf < 4; ++nf)
                    acc[m][nf] = __builtin_amdgcn_mfma_f32_16x16x32_bf16(af[m], bf[nf], acc[m][nf], 0, 0, 0);
        }
        for (int m = 0; m < 4; ++m)
            for (int nf = 0; nf < 4; ++nf) {
                int c = nc + 16 * nf + (ln & 15);
                float bb = b2s[c];
                for (int r = 0; r < 4; ++r) {
                    int n = mr + 16 * m + (ln >> 4) * 4 + r;
                    float hh = sigm(acc[m][nf][r] + bb);
                    h2t[n * 128 + (((c >> 3) ^ (n & 7)) * 8) + (c & 7)] = f2bf(hh);
                }
            }
    }
    __syncthreads();

    f32x4 acc3[4][8];
    const int mr3 = (wv >> 1) * 64;
    const int nc3 = (wv & 1) * 128;
    for (int m = 0; m < 4; ++m) for (int nf = 0; nf < 8; ++nf) acc3[m][nf] = (f32x4){0.f, 0.f, 0.f, 0.f};
    for (int kk = 0; kk < 4; ++kk) {
        int kc = kk * 4 + (ln >> 4);
        short8 af[4];
        for (int m = 0; m < 4; ++m) {
            int row = mr3 + 16 * m + (ln & 15);
            af[m] = *(const short8*)(const void*)&h2t[row * 128 + ((kc ^ (row & 7)) * 8)];
        }
        for (int nf = 0; nf < 8; ++nf) {
            int c = nc3 + 16 * nf + (ln & 15);
            short8 bf = *(const short8*)(const void*)&w3t[c * 128 + ((kc ^ (c & 7)) * 8)];
            for (int m = 0; m < 4; ++m)
                acc3[m][nf] = __builtin_amdgcn_mfma_f32_16x16x32_bf16(af[m], bf, acc3[m][nf], 0, 0, 0);
        }
    }
    __syncthreads();
    for (int m = 0; m < 4; ++m)
        for (int nf = 0; nf < 8; ++nf) {
            int c = nc3 + 16 * nf + (ln & 15);
            float bb = b3s[c];
            for (int r = 0; r < 4; ++r) {
                int n = mr3 + 16 * m + (ln >> 4) * 4 + r;
                float ss = sigm(acc3[m][nf][r] + bb);
                bufA[n * 256 + (((c >> 3) ^ (n & 7)) * 8) + (c & 7)] = f2bf(ss);
            }
        }
    __syncthreads();
    for (int i = 0; i < 16; ++i) {
        int cid = i * 256 + tid;
        int row = cid >> 5, c5 = cid & 31;
        short8 v = *(const short8*)(const void*)&bufA[row * 256 + ((c5 ^ (row & 7)) * 8)];
        int dst = inv[e0 + row];
        *(short8*)(void*)&s3p[(size_t)dst * 256 + c5 * 8] = v;
    }
}

// ---------- kernel 1: GEMM -> resp[s][slot]; chunk-32 dbuf (32KB LDS -> 4 blocks/CU) ----------
__global__ __launch_bounds__(512, 2) void k_g1(
    const float* __restrict__ bs4, const float* __restrict__ sis,
    const bfu* __restrict__ s3p, const bfu* __restrict__ w4h,
    bfu* __restrict__ resp) {

    __shared__ __align__(16) bfu s3t[2][32 * 256];   // 2 x 16K dbuf

    const int tid = threadIdx.x;
    const int wv = tid >> 6, ln = tid & 63;
    const int st = blockIdx.x >> 7;               // 0..17
    const int cg = blockIdx.x & 127;              // 0..127
    const int s0 = st * 128;
    const int wn2 = (wv & 1) * 16;                // n-group (2 x 16 rows)
    const int wsg = (wv >> 1) * 32;               // s-group (4 x 32 cols)
    const int slot00 = cg * 256;                  // 8 chunks x 32 slots

    // persistent weights in registers
    short8 bfr[2][8];
    float bssr[2], si2r[2];
#pragma unroll
    for (int nf = 0; nf < 2; ++nf) {
        int scol = s0 + wsg + 16 * nf + (ln & 15);
        const bfu* wp = &w4h[(size_t)scol * 256 + (ln >> 4) * 8];
#pragma unroll
        for (int kk = 0; kk < 8; ++kk)
            bfr[nf][kk] = *(const short8*)(const void*)&wp[kk * 32];
        bssr[nf] = (scol < NS) ? bs4[scol] : 0.0f;
        float sc = (scol < NS) ? sis[scol] : 0.0f;
        si2r[nf] = sc * sc;
    }

    const int rowS = tid >> 4;                    // 32 rows, 16 threads/row
    const int gq = tid & 15;                      // granule pair index
    const int r3 = rowS & 7;
    short8 rg0, rg1;

    auto ISSUE = [&](int c) {
        const bfu* p = s3p + ((size_t)(slot00 + c * 32 + rowS)) * 256 + gq * 16;
        rg0 = *(const short8*)(const void*)&p[0];
        rg1 = *(const short8*)(const void*)&p[8];
    };
    auto WSTAGE = [&](int buf) {
        bfu* drow = s3t[buf] + rowS * 256;
        *(short8*)(void*)&drow[(((2 * gq + 0) ^ r3) * 8)] = rg0;   // XOR hits low 3 bits only
        *(short8*)(void*)&drow[(((2 * gq + 1) ^ r3) * 8)] = rg1;
    };

    ISSUE(0); WSTAGE(0);
    __syncthreads();

    for (int c = 0; c < 8; ++c) {
        if (c + 1 < 8) ISSUE(c + 1);              // loads fly over GEMM

        // GEMM1: (32n x 256k) @ (256k x 128s), wave tile 16n x 32s
        const bfu* sb = s3t[c & 1];
        f32x4 acc0 = (f32x4){0.f,0.f,0.f,0.f};
        f32x4 acc1 = (f32x4){0.f,0.f,0.f,0.f};
        const int ar0 = wn2 + (ln & 15);
#pragma unroll
        for (int kk = 0; kk < 8; ++kk) {
            int kc = kk * 4 + (ln >> 4);
            short8 a0 = *(const short8*)(const void*)&sb[ar0 * 256 + ((kc ^ (ar0 & 7)) * 8)];
            acc0 = __builtin_amdgcn_mfma_f32_16x16x32_bf16(a0, bfr[0][kk], acc0, 0, 0, 0);
            acc1 = __builtin_amdgcn_mfma_f32_16x16x32_bf16(a0, bfr[1][kk], acc1, 0, 0, 0);
        }
        if (c + 1 < 8) WSTAGE((c + 1) & 1);       // fill idle buffer

        {   // direct 8B stores to resp (quads of lanes -> 32B contiguous)
            int sc0 = s0 + wsg + (ln & 15);
            int sc1 = sc0 + 16;
            int n0a = slot00 + c * 32 + wn2 + (ln >> 4) * 4;
            short4v pk;
#pragma unroll
            for (int r = 0; r < 4; ++r) pk[r] = (short)f2bf(si2r[0] * sigm(acc0[r] + bssr[0]));
            *(short4v*)(void*)&resp[(size_t)sc0 * 32768 + n0a] = pk;
#pragma unroll
            for (int r = 0; r < 4; ++r) pk[r] = (short)f2bf(si2r[1] * sigm(acc1[r] + bssr[1]));
            *(short4v*)(void*)&resp[(size_t)sc1 * 32768 + n0a] = pk;
        }
        __syncthreads();                          // the one barrier per chunk
    }
}

// ---------- merged aux: Eg precompute + pmt response (one launch) ----------
__global__ void k_aux(const float* __restrict__ el, const float4* __restrict__ elp,
                      const int* __restrict__ inv,
                      const float* __restrict__ Wp1, const float* __restrict__ bp1,
                      const float* __restrict__ Wp2, const float* __restrict__ bp2,
                      const float* __restrict__ psc,
                      bfu* __restrict__ Eg, bfu* __restrict__ resp) {
    int id = blockIdx.x * 256 + threadIdx.x;
    {   // Eg for slot id
        float4 e4 = elp[id];
        int bk = (int)(e4.z * 0.125f);
        bk = bk < 0 ? 0 : (bk > NBK - 1 ? NBK - 1 : bk);
        float wG = e4.w * GNRM;
#pragma unroll
        for (int j = 0; j < 16; ++j) {
            int tg = bk * 8 - 4 + j;
            float d = (float)tg + 0.5f - e4.z;
            float g = (tg >= 0 && tg < NT) ? wG * __expf(-10.0f * d * d) : 0.0f;
            Eg[j * 32768 + id] = f2bf(g);
        }
    }
    {   // pmt response for electron id -> resp rows NS..NS+11 at dst
        float x = el[id * 3], y = el[id * 3 + 1];
        float hh[28];
#pragma unroll
        for (int j = 0; j < 28; ++j)
            hh[j] = sigm(x * Wp1[j] + y * Wp1[28 + j] + bp1[j]);
        int dst = inv[id];
#pragma unroll
        for (int p = 0; p < 12; ++p) {
            float a = bp2[p];
#pragma unroll
            for (int j = 0; j < 28; ++j) a += hh[j] * Wp2[j * 12 + p];
            float sc = psc[p];
            resp[(size_t)(NS + p) * 32768 + dst] = f2bf(sigm(a) * sc * sc);
        }
    }
}

// ---------- kernel 2: wave-autonomous scatter GEMM, ILP-2 (R17/R20/R22-proven) ----------
__global__ __launch_bounds__(256, 4) void k_scat(
    const bfu* __restrict__ Eg, const bfu* __restrict__ resp,
    const int* __restrict__ counts, const int* __restrict__ offs,
    float* __restrict__ outP, float* __restrict__ outS) {

    __shared__ float ring[4 * 16 * 17];

    const int tid = threadIdx.x;
    const int ln = tid & 63, wv = tid >> 6;
    const int wid = blockIdx.x * 4 + wv;          // 0..10007
    const int sgrp = wid % NSG;
    const int grp  = (wid / NSG) % SC_NGRP;
    const int b    = wid / (NSG * SC_NGRP);

    const int bk0 = grp * SC_GBK;
    const int bk1 = (bk0 + SC_GBK < NBK) ? bk0 + SC_GBK : NBK;
    const int T_lo = bk0 * 8 - 2;
    const int scol = sgrp * 16 + (ln & 15);
    const bfu* rrow = resp + (size_t)scol * 32768;
    const bfu* erow = Eg + (size_t)(ln & 15) * 32768;
    float* ringw = ring + wv * 272;

    for (int i = ln; i < 272; i += 64) ringw[i] = 0.f;

    int F = 0;
    for (int bk = (bk0 > 0 ? bk0 - 1 : 0); bk < bk1; ++bk) {
        const int cnt = counts[b * NBK + bk];
        if (cnt == 0) continue;
        const int off = offs[b * NBK + bk];
        const int db8 = (bk - bk0) * 8;

        {   // per-wave flush of finalized ring rows [F, db8-2)
            int Fn = db8 - 2; Fn = Fn < 0 ? 0 : Fn;
            for (int tl = F + (ln >> 4); tl < Fn; tl += 4) {
                float v = ringw[(tl & 15) * 17 + (ln & 15)];
                ringw[(tl & 15) * 17 + (ln & 15)] = 0.f;
                int tg = T_lo + tl;
                if (tg >= 0 && tg < NT) {
                    if (scol < NS)
                        outS[((size_t)b * NS + scol) * NT + tg] = v;
                    else if (scol < NS + NP)
                        outP[((size_t)b * NP + (scol - NS)) * NT + tg] = v;
                }
            }
            F = (Fn > F) ? Fn : F;
        }

        const int off0 = off & ~31;
        const int nks = (off + cnt - off0 + 31) >> 5;
        const int hi = off + cnt;
        f32x4 acc = (f32x4){0.f, 0.f, 0.f, 0.f};
        f32x4 acc1 = (f32x4){0.f, 0.f, 0.f, 0.f};
        int ks = 0;
        for (; ks + 1 < nks; ks += 2) {
            const int sb0 = off0 + ks * 32 + (ln >> 4) * 8;
            const int sb1 = sb0 + 32;
            short8 af0 = *(const short8*)(const void*)&erow[sb0];
            short8 af1 = *(const short8*)(const void*)&erow[sb1];
            short8 bb0 = *(const short8*)(const void*)&rrow[sb0];
            short8 bb1 = *(const short8*)(const void*)&rrow[sb1];
            if (ks == 0 && off0 < off) {
#pragma unroll
                for (int j = 0; j < 8; ++j) { int slot = sb0 + j; if (slot < off) af0[j] = 0; }
            }
            if (off0 + ks * 32 + 64 > hi) {
#pragma unroll
                for (int j = 0; j < 8; ++j) { int slot = sb0 + j; if (slot >= hi) af0[j] = 0; }
#pragma unroll
                for (int j = 0; j < 8; ++j) { int slot = sb1 + j; if (slot >= hi) af1[j] = 0; }
            }
            acc  = __builtin_amdgcn_mfma_f32_16x16x32_bf16(af0, bb0, acc, 0, 0, 0);
            acc1 = __builtin_amdgcn_mfma_f32_16x16x32_bf16(af1, bb1, acc1, 0, 0, 0);
        }
        if (ks < nks) {
            const int sb0 = off0 + ks * 32 + (ln >> 4) * 8;
            short8 af0 = *(const short8*)(const void*)&erow[sb0];
            short8 bb0 = *(const short8*)(const void*)&rrow[sb0];
            if ((ks == 0 && off0 < off) || (off0 + ks * 32 + 32 > hi)) {
#pragma unroll
                for (int j = 0; j < 8; ++j) {
                    int slot = sb0 + j;
                    if (slot < off || slot >= hi) af0[j] = 0;
                }
            }
            acc = __builtin_amdgcn_mfma_f32_16x16x32_bf16(af0, bb0, acc, 0, 0, 0);
        }

#pragma unroll
        for (int r = 0; r < 4; ++r) {
            int tl = db8 - 2 + (ln >> 4) * 4 + r;
            if (tl >= 0 && tl < SC_TW)
                ringw[(tl & 15) * 17 + (ln & 15)] += acc[r] + acc1[r];
        }
    }

    // final flush [F, 32)
    for (int tl = F + (ln >> 4); tl < SC_TW; tl += 4) {
        float v = ringw[(tl & 15) * 17 + (ln & 15)];
        int tg = T_lo + tl;
        if (tg >= 0 && tg < NT) {
            if (scol < NS)
                outS[((size_t)b * NS + scol) * NT + tg] = v;
            else if (scol < NS + NP)
                outP[((size_t)b * NP + (scol - NS)) * NT + tg] = v;
        }
    }
}

extern "C" void kernel_launch(void* const* d_in, const int* in_sizes, int n_in,
                              void* d_out, int out_size, void* d_ws, size_t ws_size,
                              hipStream_t stream) {
    const float* el  = (const float*)d_in[0];
    const float* wt  = (const float*)d_in[1];
    const float* Wp1 = (const float*)d_in[2];
    const float* bp1 = (const float*)d_in[3];
    const float* Wp2 = (const float*)d_in[4];
    const float* bp2 = (const float*)d_in[5];
    const float* psc = (const float*)d_in[6];
    const float* Ws1 = (const float*)d_in[7];
    const float* bs1 = (const float*)d_in[8];
    const float* Ws2 = (const float*)d_in[9];
    const float* bs2 = (const float*)d_in[10];
    const float* Ws3 = (const float*)d_in[11];
    const float* bs3 = (const float*)d_in[12];
    const float* Ws4 = (const float*)d_in[13];
    const float* bs4 = (const float*)d_in[14];
    const float* sis = (const float*)d_in[15];
    float* out = (float*)d_out;

    char* ws = (char*)d_ws;
    bfu* w2h     = (bfu*)(ws);                    // 16384
    bfu* w3h     = (bfu*)(ws + 16384);            // 65536
    bfu* w4h     = (bfu*)(ws + 81920);            // 1179648 (k_g1 input; reused as Eg after)
    bfu* Eg      = (bfu*)(ws + 81920);            // 1048576 (written by k_aux AFTER k_g1)
    bfu* s3p     = (bfu*)(ws + 1261568);          // 16777216 (bucket-sorted)
    int* counts  = (int*)(ws + 18038784);
    int* offs    = (int*)(ws + 18042880);
    int* cursors = (int*)(ws + 18046976);
    int* inv     = (int*)(ws + 18051072);         // 131072 -> 18182144
    float4* elp  = (float4*)(ws + 18182144);      // 524288  -> 18706432
    bfu* resp    = (bfu*)(ws + 18706432);         // 150994944 -> 169701376 (proven present)

    hipMemsetAsync(counts, 0, 4096, stream);
    hipMemsetAsync(cursors, 0, 4096, stream);
    // out fully covered by k_scat's exact (tick x column) partition flush

    k_prep<<<2464, 256, 0, stream>>>(Ws2, Ws3, Ws4, w2h, w3h, w4h);
    k_count<<<128, 256, 0, stream>>>(el, counts);
    k_scan<<<1, 512, 0, stream>>>(counts, offs);
    k_scatter<<<128, 256, 0, stream>>>(el, wt, offs, cursors, inv, elp);
    k_mlp<<<256, 256, 0, stream>>>(el, Ws1, bs1, bs2, bs3, w2h, w3h, inv, s3p);
    k_g1<<<18 * 128, 512, 0, stream>>>(bs4, sis, s3p, w4h, resp);
    k_aux<<<128, 256, 0, stream>>>(el, elp, inv, Wp1, bp1, Wp2, bp2, psc, Eg, resp);
    k_scat<<<(4 * SC_NGRP * NSG) / 4, 256, 0, stream>>>(Eg, resp, counts, offs,
                                                        out, out + 4 * NP * NT);
}

// Round 24
// 210.431 us; speedup vs baseline: 1.0083x; 1.0083x over previous
//
#include <hip/hip_runtime.h>

typedef short short8 __attribute__((ext_vector_type(8)));
typedef short short4v __attribute__((ext_vector_type(4)));
typedef float f32x4 __attribute__((ext_vector_type(4)));

#define NT 550
#define NS 2209
#define NP 12
#define NBK 69
#define SC_NGRP 18
#define SC_GBK 4
#define SC_TW 32
#define NSG 139
#define GNRM 3.9894228040143f

typedef unsigned short bfu;

__device__ __forceinline__ bfu f2bf(float f) {
    unsigned int u = __float_as_uint(f);
    unsigned int r = (u + 0x7fffu + ((u >> 16) & 1u)) >> 16;
    return (bfu)r;
}

__device__ __forceinline__ float sigm(float x) {
    return __builtin_amdgcn_rcpf(1.0f + __expf(-x));
}

// ---------- weight conversion: fp32 -> transposed bf16 ----------
__global__ void k_prep(const float* __restrict__ W2, const float* __restrict__ W3,
                       const float* __restrict__ W4,
                       bfu* __restrict__ w2h, bfu* __restrict__ w3h, bfu* __restrict__ w4h) {
    int id = blockIdx.x * 256 + threadIdx.x;
    if (id < 8192) {
        int c = id >> 6, k = id & 63;
        w2h[id] = f2bf(W2[k * 128 + c]);
    } else if (id < 8192 + 32768) {
        int j = id - 8192;
        int c = j >> 7, k = j & 127;
        w3h[j] = f2bf(W3[k * 256 + c]);
    } else {
        int j = id - 40960;
        int s = j >> 8, k = j & 255;
        w4h[j] = f2bf(s < NS ? W4[k * NS + s] : 0.0f);
    }
}

// ---------- bucketing ----------
__global__ void k_count(const float* __restrict__ el, int* __restrict__ counts) {
    int id = blockIdx.x * 256 + threadIdx.x;
    float z = el[id * 3 + 2];
    int bk = (int)(z * 0.125f);
    bk = bk < 0 ? 0 : (bk > NBK - 1 ? NBK - 1 : bk);
    atomicAdd(&counts[(id >> 13) * NBK + bk], 1);
}

__global__ void k_scan(const int* __restrict__ counts, int* __restrict__ offs) {
    __shared__ int a[512];
    int tid = threadIdx.x;
    int v = (tid < 4 * NBK) ? counts[tid] : 0;
    a[tid] = v;
    __syncthreads();
    for (int s = 1; s < 512; s <<= 1) {
        int t = (tid >= s) ? a[tid - s] : 0;
        __syncthreads();
        a[tid] += t;
        __syncthreads();
    }
    if (tid < 4 * NBK) offs[tid] = a[tid] - v;
}

__global__ void k_scatter(const float* __restrict__ el, const float* __restrict__ wt,
                          const int* __restrict__ offs, int* __restrict__ cur,
                          int* __restrict__ inv, float4* __restrict__ elp) {
    int id = blockIdx.x * 256 + threadIdx.x;
    float x = el[id * 3], y = el[id * 3 + 1], z = el[id * 3 + 2];
    int bk = (int)(z * 0.125f);
    bk = bk < 0 ? 0 : (bk > NBK - 1 ? NBK - 1 : bk);
    int key = (id >> 13) * NBK + bk;
    int pos = offs[key] + atomicAdd(&cur[key], 1);
    inv[id] = pos;
    elp[pos] = make_float4(x, y, z, wt[id]);
}

// ---------- phase A: sipm MLP layers 1-3 -> s3p (BUCKET-SORTED, bf16) ----------
__global__ __launch_bounds__(256, 1) void k_mlp(
    const float* __restrict__ el,
    const float* __restrict__ Ws1, const float* __restrict__ bs1,
    const float* __restrict__ bs2, const float* __restrict__ bs3,
    const bfu* __restrict__ w2h, const bfu* __restrict__ w3h,
    const int* __restrict__ inv, bfu* __restrict__ s3p) {

    __shared__ __align__(16) bfu bufA[32768];
    __shared__ __align__(16) bfu w3t[32768];
    __shared__ float xyb[256];
    __shared__ float s1w[128];
    __shared__ float b1s[64], b2s[128], b3s[256];

    bfu* h1t = bufA;
    bfu* w2t = bufA + 8192;
    bfu* h2t = bufA + 16384;

    const int tid = threadIdx.x;
    const int wv = tid >> 6, ln = tid & 63;
    const int e0 = blockIdx.x * 128;

    if (tid < 128) s1w[tid] = Ws1[tid];
    if (tid < 64) b1s[tid] = bs1[tid];
    if (tid < 128) b2s[tid] = bs2[tid];
    b3s[tid] = bs3[tid];

    if (tid < 128) {
        int e = e0 + tid;
        xyb[tid * 2] = el[e * 3]; xyb[tid * 2 + 1] = el[e * 3 + 1];
    }
    for (int i = 0; i < 4; ++i) {
        int cid = i * 256 + tid;
        int row = cid >> 3, c5 = cid & 7;
        short8 v = *(const short8*)(const void*)&w2h[row * 64 + c5 * 8];
        *(short8*)(void*)&w2t[row * 64 + ((c5 ^ (row & 7)) * 8)] = v;
    }
    for (int i = 0; i < 16; ++i) {
        int cid = i * 256 + tid;
        int row = cid >> 4, c5 = cid & 15;
        short8 v = *(const short8*)(const void*)&w3h[row * 128 + c5 * 8];
        *(short8*)(void*)&w3t[row * 128 + ((c5 ^ (row & 7)) * 8)] = v;
    }
    __syncthreads();

    {
        int n = tid & 127;
        int j0 = (tid >> 7) * 32;
        float xx = xyb[n * 2], yy = xyb[n * 2 + 1];
        for (int jj = 0; jj < 32; ++jj) {
            int j = j0 + jj;
            float h = sigm(xx * s1w[j] + yy * s1w[64 + j] + b1s[j]);
            h1t[n * 64 + (((j >> 3) ^ (n & 7)) * 8) + (j & 7)] = f2bf(h);
        }
    }
    __syncthreads();

    {
        const int mr = (wv >> 1) * 64;
        const int nc = (wv & 1) * 64;
        f32x4 acc[4][4];
        for (int m = 0; m < 4; ++m) for (int nf = 0; nf < 4; ++nf) acc[m][nf] = (f32x4){0.f, 0.f, 0.f, 0.f};
        for (int kk = 0; kk < 2; ++kk) {
            int kc = kk * 4 + (ln >> 4);
            short8 af[4], bf[4];
            for (int m = 0; m < 4; ++m) {
                int row = mr + 16 * m + (ln & 15);
                af[m] = *(const short8*)(const void*)&h1t[row * 64 + ((kc ^ (row & 7)) * 8)];
            }
            for (int nf = 0; nf < 4; ++nf) {
                int c = nc + 16 * nf + (ln & 15);
                bf[nf] = *(const short8*)(const void*)&w2t[c * 64 + ((kc ^ (c & 7)) * 8)];
            }
            for (int m = 0; m < 4; ++m)
                for (int nf = 0; nf < 4; ++nf)
                    acc[m][nf] = __builtin_amdgcn_mfma_f32_16x16x32_bf16(af[m], bf[nf], acc[m][nf], 0, 0, 0);
        }
        for (int m = 0; m < 4; ++m)
            for (int nf = 0; nf < 4; ++nf) {
                int c = nc + 16 * nf + (ln & 15);
                float bb = b2s[c];
                for (int r = 0; r < 4; ++r) {
                    int n = mr + 16 * m + (ln >> 4) * 4 + r;
                    float hh = sigm(acc[m][nf][r] + bb);
                    h2t[n * 128 + (((c >> 3) ^ (n & 7)) * 8) + (c & 7)] = f2bf(hh);
                }
            }
    }
    __syncthreads();

    f32x4 acc3[4][8];
    const int mr3 = (wv >> 1) * 64;
    const int nc3 = (wv & 1) * 128;
    for (int m = 0; m < 4; ++m) for (int nf = 0; nf < 8; ++nf) acc3[m][nf] = (f32x4){0.f, 0.f, 0.f, 0.f};
    for (int kk = 0; kk < 4; ++kk) {
        int kc = kk * 4 + (ln >> 4);
        short8 af[4];
        for (int m = 0; m < 4; ++m) {
            int row = mr3 + 16 * m + (ln & 15);
            af[m] = *(const short8*)(const void*)&h2t[row * 128 + ((kc ^ (row & 7)) * 8)];
        }
        for (int nf = 0; nf < 8; ++nf) {
            int c = nc3 + 16 * nf + (ln & 15);
            short8 bf = *(const short8*)(const void*)&w3t[c * 128 + ((kc ^ (c & 7)) * 8)];
            for (int m = 0; m < 4; ++m)
                acc3[m][nf] = __builtin_amdgcn_mfma_f32_16x16x32_bf16(af[m], bf, acc3[m][nf], 0, 0, 0);
        }
    }
    __syncthreads();
    for (int m = 0; m < 4; ++m)
        for (int nf = 0; nf < 8; ++nf) {
            int c = nc3 + 16 * nf + (ln & 15);
            float bb = b3s[c];
            for (int r = 0; r < 4; ++r) {
                int n = mr3 + 16 * m + (ln >> 4) * 4 + r;
                float ss = sigm(acc3[m][nf][r] + bb);
                bufA[n * 256 + (((c >> 3) ^ (n & 7)) * 8) + (c & 7)] = f2bf(ss);
            }
        }
    __syncthreads();
    for (int i = 0; i < 16; ++i) {
        int cid = i * 256 + tid;
        int row = cid >> 5, c5 = cid & 31;
        short8 v = *(const short8*)(const void*)&bufA[row * 256 + ((c5 ^ (row & 7)) * 8)];
        int dst = inv[e0 + row];
        *(short8*)(void*)&s3p[(size_t)dst * 256 + c5 * 8] = v;
    }
}

// ---------- kernel 1: GEMM -> resp[s][slot]; chunk-64 dbuf, grid 2304 (R22-proven) ----------
__global__ __launch_bounds__(512, 2) void k_g1(
    const float* __restrict__ bs4, const float* __restrict__ sis,
    const bfu* __restrict__ s3p, const bfu* __restrict__ w4h,
    bfu* __restrict__ resp) {

    __shared__ __align__(16) bfu s3t[2][64 * 256];   // 2 x 32K dbuf

    const int tid = threadIdx.x;
    const int wv = tid >> 6, ln = tid & 63;
    const int st = blockIdx.x >> 7;               // 0..17
    const int cg = blockIdx.x & 127;              // 0..127
    const int s0 = st * 128;
    const int wn2 = (wv & 1) * 32;                // n-group (2 x 32 rows)
    const int wsg = (wv >> 1) * 32;               // s-group (4 x 32 cols)
    const int slot00 = cg * 256;                  // 4 chunks x 64 slots

    // persistent weights in registers
    short8 bfr[2][8];
    float bssr[2], si2r[2];
#pragma unroll
    for (int nf = 0; nf < 2; ++nf) {
        int scol = s0 + wsg + 16 * nf + (ln & 15);
        const bfu* wp = &w4h[(size_t)scol * 256 + (ln >> 4) * 8];
#pragma unroll
        for (int kk = 0; kk < 8; ++kk)
            bfr[nf][kk] = *(const short8*)(const void*)&wp[kk * 32];
        bssr[nf] = (scol < NS) ? bs4[scol] : 0.0f;
        float sc = (scol < NS) ? sis[scol] : 0.0f;
        si2r[nf] = sc * sc;
    }

    const int rowS = tid >> 3;                    // 64 rows, 8 threads/row
    const int gq = tid & 7;                       // base granule
    const int r3 = rowS & 7;
    short8 rg0, rg1, rg2, rg3;

    auto ISSUE = [&](int c) {
        const bfu* p = s3p + ((size_t)(slot00 + c * 64 + rowS)) * 256 + gq * 8;
        rg0 = *(const short8*)(const void*)&p[0];
        rg1 = *(const short8*)(const void*)&p[64];
        rg2 = *(const short8*)(const void*)&p[128];
        rg3 = *(const short8*)(const void*)&p[192];
    };
    auto WSTAGE = [&](int buf) {
        bfu* drow = s3t[buf] + rowS * 256;
        *(short8*)(void*)&drow[(((0 * 8 + gq) ^ r3) * 8)] = rg0;   // XOR hits low 3 bits only
        *(short8*)(void*)&drow[(((1 * 8 + gq) ^ r3) * 8)] = rg1;
        *(short8*)(void*)&drow[(((2 * 8 + gq) ^ r3) * 8)] = rg2;
        *(short8*)(void*)&drow[(((3 * 8 + gq) ^ r3) * 8)] = rg3;
    };

    ISSUE(0); WSTAGE(0);
    __syncthreads();

    for (int c = 0; c < 4; ++c) {
        if (c + 1 < 4) ISSUE(c + 1);              // loads fly over GEMM

        // GEMM1: (64n x 256k) @ (256k x 128s), wave tile 32n x 32s
        const bfu* sb = s3t[c & 1];
        f32x4 acc00 = (f32x4){0.f,0.f,0.f,0.f};
        f32x4 acc01 = (f32x4){0.f,0.f,0.f,0.f};
        f32x4 acc10 = (f32x4){0.f,0.f,0.f,0.f};
        f32x4 acc11 = (f32x4){0.f,0.f,0.f,0.f};
        const int ar0 = wn2 + (ln & 15), ar1 = wn2 + 16 + (ln & 15);
#pragma unroll
        for (int kk = 0; kk < 8; ++kk) {
            int kc = kk * 4 + (ln >> 4);
            short8 a0 = *(const short8*)(const void*)&sb[ar0 * 256 + ((kc ^ (ar0 & 7)) * 8)];
            short8 a1 = *(const short8*)(const void*)&sb[ar1 * 256 + ((kc ^ (ar1 & 7)) * 8)];
            acc00 = __builtin_amdgcn_mfma_f32_16x16x32_bf16(a0, bfr[0][kk], acc00, 0, 0, 0);
            acc01 = __builtin_amdgcn_mfma_f32_16x16x32_bf16(a0, bfr[1][kk], acc01, 0, 0, 0);
            acc10 = __builtin_amdgcn_mfma_f32_16x16x32_bf16(a1, bfr[0][kk], acc10, 0, 0, 0);
            acc11 = __builtin_amdgcn_mfma_f32_16x16x32_bf16(a1, bfr[1][kk], acc11, 0, 0, 0);
        }
        if (c + 1 < 4) WSTAGE((c + 1) & 1);       // fill idle buffer

        {   // direct 8B stores to resp (quads of lanes -> 32B contiguous)
            int sc0 = s0 + wsg + (ln & 15);
            int sc1 = sc0 + 16;
            int base = slot00 + c * 64;
            int n0a = base + wn2 + (ln >> 4) * 4;
            int n0b = n0a + 16;
            short4v pk;
#pragma unroll
            for (int r = 0; r < 4; ++r) pk[r] = (short)f2bf(si2r[0] * sigm(acc00[r] + bssr[0]));
            *(short4v*)(void*)&resp[(size_t)sc0 * 32768 + n0a] = pk;
#pragma unroll
            for (int r = 0; r < 4; ++r) pk[r] = (short)f2bf(si2r[1] * sigm(acc01[r] + bssr[1]));
            *(short4v*)(void*)&resp[(size_t)sc1 * 32768 + n0a] = pk;
#pragma unroll
            for (int r = 0; r < 4; ++r) pk[r] = (short)f2bf(si2r[0] * sigm(acc10[r] + bssr[0]));
            *(short4v*)(void*)&resp[(size_t)sc0 * 32768 + n0b] = pk;
#pragma unroll
            for (int r = 0; r < 4; ++r) pk[r] = (short)f2bf(si2r[1] * sigm(acc11[r] + bssr[1]));
            *(short4v*)(void*)&resp[(size_t)sc1 * 32768 + n0b] = pk;
        }
        __syncthreads();                          // the one barrier per chunk
    }
}

// ---------- merged aux: Eg precompute + pmt response (one launch) ----------
__global__ void k_aux(const float* __restrict__ el, const float4* __restrict__ elp,
                      const int* __restrict__ inv,
                      const float* __restrict__ Wp1, const float* __restrict__ bp1,
                      const float* __restrict__ Wp2, const float* __restrict__ bp2,
                      const float* __restrict__ psc,
                      bfu* __restrict__ Eg, bfu* __restrict__ resp) {
    int id = blockIdx.x * 256 + threadIdx.x;
    {   // Eg for slot id
        float4 e4 = elp[id];
        int bk = (int)(e4.z * 0.125f);
        bk = bk < 0 ? 0 : (bk > NBK - 1 ? NBK - 1 : bk);
        float wG = e4.w * GNRM;
#pragma unroll
        for (int j = 0; j < 16; ++j) {
            int tg = bk * 8 - 4 + j;
            float d = (float)tg + 0.5f - e4.z;
            float g = (tg >= 0 && tg < NT) ? wG * __expf(-10.0f * d * d) : 0.0f;
            Eg[j * 32768 + id] = f2bf(g);
        }
    }
    {   // pmt response for electron id -> resp rows NS..NS+11 at dst
        float x = el[id * 3], y = el[id * 3 + 1];
        float hh[28];
#pragma unroll
        for (int j = 0; j < 28; ++j)
            hh[j] = sigm(x * Wp1[j] + y * Wp1[28 + j] + bp1[j]);
        int dst = inv[id];
#pragma unroll
        for (int p = 0; p < 12; ++p) {
            float a = bp2[p];
#pragma unroll
            for (int j = 0; j < 28; ++j) a += hh[j] * Wp2[j * 12 + p];
            float sc = psc[p];
            resp[(size_t)(NS + p) * 32768 + dst] = f2bf(sigm(a) * sc * sc);
        }
    }
}

// ---------- kernel 2: wave-autonomous scatter GEMM, ILP-2 (R17/R20/R22-proven) ----------
__global__ __launch_bounds__(256, 4) void k_scat(
    const bfu* __restrict__ Eg, const bfu* __restrict__ resp,
    const int* __restrict__ counts, const int* __restrict__ offs,
    float* __restrict__ outP, float* __restrict__ outS) {

    __shared__ float ring[4 * 16 * 17];

    const int tid = threadIdx.x;
    const int ln = tid & 63, wv = tid >> 6;
    const int wid = blockIdx.x * 4 + wv;          // 0..10007
    const int sgrp = wid % NSG;
    const int grp  = (wid / NSG) % SC_NGRP;
    const int b    = wid / (NSG * SC_NGRP);

    const int bk0 = grp * SC_GBK;
    const int bk1 = (bk0 + SC_GBK < NBK) ? bk0 + SC_GBK : NBK;
    const int T_lo = bk0 * 8 - 2;
    const int scol = sgrp * 16 + (ln & 15);
    const bfu* rrow = resp + (size_t)scol * 32768;
    const bfu* erow = Eg + (size_t)(ln & 15) * 32768;
    float* ringw = ring + wv * 272;

    for (int i = ln; i < 272; i += 64) ringw[i] = 0.f;

    int F = 0;
    for (int bk = (bk0 > 0 ? bk0 - 1 : 0); bk < bk1; ++bk) {
        const int cnt = counts[b * NBK + bk];
        if (cnt == 0) continue;
        const int off = offs[b * NBK + bk];
        const int db8 = (bk - bk0) * 8;

        {   // per-wave flush of finalized ring rows [F, db8-2)
            int Fn = db8 - 2; Fn = Fn < 0 ? 0 : Fn;
            for (int tl = F + (ln >> 4); tl < Fn; tl += 4) {
                float v = ringw[(tl & 15) * 17 + (ln & 15)];
                ringw[(tl & 15) * 17 + (ln & 15)] = 0.f;
                int tg = T_lo + tl;
                if (tg >= 0 && tg < NT) {
                    if (scol < NS)
                        outS[((size_t)b * NS + scol) * NT + tg] = v;
                    else if (scol < NS + NP)
                        outP[((size_t)b * NP + (scol - NS)) * NT + tg] = v;
                }
            }
            F = (Fn > F) ? Fn : F;
        }

        const int off0 = off & ~31;
        const int nks = (off + cnt - off0 + 31) >> 5;
        const int hi = off + cnt;
        f32x4 acc = (f32x4){0.f, 0.f, 0.f, 0.f};
        f32x4 acc1 = (f32x4){0.f, 0.f, 0.f, 0.f};
        int ks = 0;
        for (; ks + 1 < nks; ks += 2) {
            const int sb0 = off0 + ks * 32 + (ln >> 4) * 8;
            const int sb1 = sb0 + 32;
            short8 af0 = *(const short8*)(const void*)&erow[sb0];
            short8 af1 = *(const short8*)(const void*)&erow[sb1];
            short8 bb0 = *(const short8*)(const void*)&rrow[sb0];
            short8 bb1 = *(const short8*)(const void*)&rrow[sb1];
            if (ks == 0 && off0 < off) {
#pragma unroll
                for (int j = 0; j < 8; ++j) { int slot = sb0 + j; if (slot < off) af0[j] = 0; }
            }
            if (off0 + ks * 32 + 64 > hi) {
#pragma unroll
                for (int j = 0; j < 8; ++j) { int slot = sb0 + j; if (slot >= hi) af0[j] = 0; }
#pragma unroll
                for (int j = 0; j < 8; ++j) { int slot = sb1 + j; if (slot >= hi) af1[j] = 0; }
            }
            acc  = __builtin_amdgcn_mfma_f32_16x16x32_bf16(af0, bb0, acc, 0, 0, 0);
            acc1 = __builtin_amdgcn_mfma_f32_16x16x32_bf16(af1, bb1, acc1, 0, 0, 0);
        }
        if (ks < nks) {
            const int sb0 = off0 + ks * 32 + (ln >> 4) * 8;
            short8 af0 = *(const short8*)(const void*)&erow[sb0];
            short8 bb0 = *(const short8*)(const void*)&rrow[sb0];
            if ((ks == 0 && off0 < off) || (off0 + ks * 32 + 32 > hi)) {
#pragma unroll
                for (int j = 0; j < 8; ++j) {
                    int slot = sb0 + j;
                    if (slot < off || slot >= hi) af0[j] = 0;
                }
            }
            acc = __builtin_amdgcn_mfma_f32_16x16x32_bf16(af0, bb0, acc, 0, 0, 0);
        }

#pragma unroll
        for (int r = 0; r < 4; ++r) {
            int tl = db8 - 2 + (ln >> 4) * 4 + r;
            if (tl >= 0 && tl < SC_TW)
                ringw[(tl & 15) * 17 + (ln & 15)] += acc[r] + acc1[r];
        }
    }

    // final flush [F, 32)
    for (int tl = F + (ln >> 4); tl < SC_TW; tl += 4) {
        float v = ringw[(tl & 15) * 17 + (ln & 15)];
        int tg = T_lo + tl;
        if (tg >= 0 && tg < NT) {
            if (scol < NS)
                outS[((size_t)b * NS + scol) * NT + tg] = v;
            else if (scol < NS + NP)
                outP[((size_t)b * NP + (scol - NS)) * NT + tg] = v;
        }
    }
}

extern "C" void kernel_launch(void* const* d_in, const int* in_sizes, int n_in,
                              void* d_out, int out_size, void* d_ws, size_t ws_size,
                              hipStream_t stream) {
    const float* el  = (const float*)d_in[0];
    const float* wt  = (const float*)d_in[1];
    const float* Wp1 = (const float*)d_in[2];
    const float* bp1 = (const float*)d_in[3];
    const float* Wp2 = (const float*)d_in[4];
    const float* bp2 = (const float*)d_in[5];
    const float* psc = (const float*)d_in[6];
    const float* Ws1 = (const float*)d_in[7];
    const float* bs1 = (const float*)d_in[8];
    const float* Ws2 = (const float*)d_in[9];
    const float* bs2 = (const float*)d_in[10];
    const float* Ws3 = (const float*)d_in[11];
    const float* bs3 = (const float*)d_in[12];
    const float* Ws4 = (const float*)d_in[13];
    const float* bs4 = (const float*)d_in[14];
    const float* sis = (const float*)d_in[15];
    float* out = (float*)d_out;

    char* ws = (char*)d_ws;
    bfu* w2h     = (bfu*)(ws);                    // 16384
    bfu* w3h     = (bfu*)(ws + 16384);            // 65536
    bfu* w4h     = (bfu*)(ws + 81920);            // 1179648 (k_g1 input; reused as Eg after)
    bfu* Eg      = (bfu*)(ws + 81920);            // 1048576 (written by k_aux AFTER k_g1)
    bfu* s3p     = (bfu*)(ws + 1261568);          // 16777216 (bucket-sorted)
    int* counts  = (int*)(ws + 18038784);
    int* offs    = (int*)(ws + 18042880);
    int* cursors = (int*)(ws + 18046976);
    int* inv     = (int*)(ws + 18051072);         // 131072 -> 18182144
    float4* elp  = (float4*)(ws + 18182144);      // 524288  -> 18706432
    bfu* resp    = (bfu*)(ws + 18706432);         // 150994944 -> 169701376 (proven present)

    hipMemsetAsync(counts, 0, 4096, stream);
    hipMemsetAsync(cursors, 0, 4096, stream);
    // out fully covered by k_scat's exact (tick x column) partition flush

    k_prep<<<2464, 256, 0, stream>>>(Ws2, Ws3, Ws4, w2h, w3h, w4h);
    k_count<<<128, 256, 0, stream>>>(el, counts);
    k_scan<<<1, 512, 0, stream>>>(counts, offs);
    k_scatter<<<128, 256, 0, stream>>>(el, wt, offs, cursors, inv, elp);
    k_mlp<<<256, 256, 0, stream>>>(el, Ws1, bs1, bs2, bs3, w2h, w3h, inv, s3p);
    k_g1<<<18 * 128, 512, 0, stream>>>(bs4, sis, s3p, w4h, resp);
    k_aux<<<128, 256, 0, stream>>>(el, elp, inv, Wp1, bp1, Wp2, bp2, psc, Eg, resp);
    k_scat<<<(4 * SC_NGRP * NSG) / 4, 256, 0, stream>>>(Eg, resp, counts, offs,
                                                        out, out + 4 * NP * NT);
}